// Round 16
// baseline (482.642 us; speedup 1.0000x reference)
//
#include <hip/hip_runtime.h>
#include <hip/hip_bf16.h>
#include <stdint.h>

typedef __hip_bfloat16 bf16;
typedef __attribute__((ext_vector_type(8))) __bf16 bf16x8;
typedef __attribute__((ext_vector_type(4))) float f32x4;
typedef __attribute__((ext_vector_type(16))) float f32x16;

__device__ __forceinline__ void gld16(void* lds, const void* g) {
  __builtin_amdgcn_global_load_lds(
      (const __attribute__((address_space(1))) void*)(uintptr_t)(g),
      (__attribute__((address_space(3))) void*)(uint32_t)(uintptr_t)(lds),
      16, 0, 0);
}

__device__ __forceinline__ uint16_t f2bf(float f) {
  union { bf16 h; uint16_t u; } x; x.h = __float2bfloat16(f); return x.u;
}
__device__ __forceinline__ float bf2f(uint16_t v) {
  union { uint32_t u; float f; } x; x.u = ((uint32_t)v) << 16; return x.f;
}
__device__ __forceinline__ uint32_t pk2(float lo, float hi) {
  uint32_t r;
  asm("v_cvt_pk_bf16_f32 %0, %1, %2" : "=v"(r) : "v"(lo), "v"(hi));
  return r;
}

// ------- fused f32 -> bf16 cast of x, wq, wkv, wp (one launch) -------
__global__ __launch_bounds__(256) void k_cast4(
    const float4* __restrict__ x, const float4* __restrict__ wq,
    const float4* __restrict__ wkv, const float4* __restrict__ wp,
    uint2* __restrict__ xb, uint2* __restrict__ wqb,
    uint2* __restrict__ wkvb, uint2* __restrict__ wpb) {
  int i = blockIdx.x * 256 + threadIdx.x;  // 0 .. 14680064
  const float4* src;
  uint2* dst;
  int o;
  if (i < 4194304) { src = x; dst = xb; o = i; }
  else if (i < 8388608) { src = wq; dst = wqb; o = i - 4194304; }
  else if (i < 10485760) { src = wkv; dst = wkvb; o = i - 8388608; }
  else { src = wp; dst = wpb; o = i - 10485760; }
  float4 v = src[o];
  uint32_t a = ((uint32_t)f2bf(v.y) << 16) | f2bf(v.x);
  uint32_t b = ((uint32_t)f2bf(v.w) << 16) | f2bf(v.z);
  dst[o] = make_uint2(a, b);
}

// ---------------- (MB64*64)x256 NT GEMM, dual-schedule K-loop ----------------
// r13-verified sync skeleton (one __syncthreads per tile, reads-first staging
// behind).  NEW: the two waves sharing a SIMD get ANTIPHASE schedules --
// waves 0-3: read-first 1-deep ping-pong (r13 form); waves 4-7: MFMA-first
// 2-deep (top-reads B+A0+A1; per phase: wait -> MFMA p -> read A(p+2); the
// freed buffer (p&1) == ((p+2)&1) so ping-pong holds at distance 2).  Breaks
// the in-phase lockstep that serialized LDS bursts with MFMA bursts
// (measured: tile time == LDS cycles + MFMA cycles, MfmaUtil 45%).
template <int OUT_BF16, int MB64>
__global__ __launch_bounds__(512, 2) void k_gemm256(
    const bf16* __restrict__ A, const bf16* __restrict__ B,
    const float* __restrict__ bias, void* __restrict__ C,
    int M, int N, int K, int gx) {
  constexpr int MPP = MB64 / 2;
  constexpr int MI = MB64 * 2;
  constexpr int ABYTES = MB64 * 8192;
  constexpr int SLOT = ABYTES + 32768;
  __shared__ __align__(16) char lds[2 * SLOT];
  const int tid = threadIdx.x;
  const int lane = tid & 63;
  const int w = tid >> 6;
  const int wm = w >> 2;
  const int wn = w & 3;
  const int lm = lane & 15;
  const int lg = lane >> 4;

  const int nwg = gridDim.x;
  const int cpx = nwg >> 3;
  const int bid0 = blockIdx.x;
  const int bid = (bid0 & 7) * cpx + (bid0 >> 3);
  const int bx = bid % gx;
  const int by = bid / gx;
  const size_t bm = (size_t)by * (MB64 * 64);
  const size_t bn = (size_t)bx * 256;

  const int srow = tid >> 3;
  const int scb = ((tid & 7) * 16) ^ ((srow & 7) << 4);
  const char* asrc[MB64];
  const char* bsrc[4];
#pragma unroll
  for (int j = 0; j < MB64; ++j)
    asrc[j] = (const char*)(A + (bm + j * 64 + srow) * K) + scb;
#pragma unroll
  for (int j = 0; j < 4; ++j)
    bsrc[j] = (const char*)(B + (bn + j * 64 + srow) * K) + scb;
  const int ldst = tid * 16;

  const int colb0 = (lg * 16) ^ ((lm & 7) << 4);
  const int colb1 = colb0 ^ 64;

  f32x4 acc[MI][4];
#pragma unroll
  for (int i = 0; i < MI; ++i)
#pragma unroll
    for (int j = 0; j < 4; ++j) acc[i][j] = (f32x4){0.f, 0.f, 0.f, 0.f};

  const int NT = K >> 6;

  {
    char* la = lds;
    char* lb = lds + ABYTES;
#pragma unroll
    for (int j = 0; j < MB64; ++j) gld16(la + j * 8192 + ldst, asrc[j]);
#pragma unroll
    for (int j = 0; j < 4; ++j) gld16(lb + j * 8192 + ldst, bsrc[j]);
  }
  __syncthreads();  // tile 0 landed

  for (int t = 0; t < NT; ++t) {
    const int slot = t & 1;
    const char* la = lds + slot * SLOT;
    const char* lb = la + ABYTES;

    // tile-top reads (both schedules): all B-frags + A-frags for phase 0
    bf16x8 bfrag[4][2];
#pragma unroll
    for (int ni = 0; ni < 4; ++ni) {
      const int br = wn * 64 + ni * 16 + lm;
      bfrag[ni][0] = *(const bf16x8*)(lb + br * 128 + colb0);
      bfrag[ni][1] = *(const bf16x8*)(lb + br * 128 + colb1);
    }
    bf16x8 afA[MPP][2], afB[MPP][2];
#pragma unroll
    for (int q = 0; q < MPP; ++q) {
      const int ar = wm * (MB64 * 32) + q * 16 + lm;
      afA[q][0] = *(const bf16x8*)(la + ar * 128 + colb0);
      afA[q][1] = *(const bf16x8*)(la + ar * 128 + colb1);
    }

    if (t + 1 < NT) {
      char* na = lds + (slot ^ 1) * SLOT;
      char* nb = na + ABYTES;
      const size_t ko = (size_t)(t + 1) * 128;
#pragma unroll
      for (int j = 0; j < MB64; ++j) gld16(na + j * 8192 + ldst, asrc[j] + ko);
#pragma unroll
      for (int j = 0; j < 4; ++j) gld16(nb + j * 8192 + ldst, bsrc[j] + ko);
    }

    if (wm == 0) {
      // -------- schedule A (read-first, 1-deep; r13-verified) --------
#pragma unroll
      for (int p = 0; p < 4; ++p) {
        auto& cur = (p & 1) ? afB : afA;
        auto& nxt = (p & 1) ? afA : afB;
        if (p < 3) {
#pragma unroll
          for (int q = 0; q < MPP; ++q) {
            const int ar = wm * (MB64 * 32) + ((p + 1) * MPP + q) * 16 + lm;
            nxt[q][0] = *(const bf16x8*)(la + ar * 128 + colb0);
            nxt[q][1] = *(const bf16x8*)(la + ar * 128 + colb1);
          }
          if constexpr (MPP == 2)
            asm volatile("s_waitcnt lgkmcnt(4)" ::: "memory");
          else
            asm volatile("s_waitcnt lgkmcnt(2)" ::: "memory");
        } else {
          asm volatile("s_waitcnt lgkmcnt(0)" ::: "memory");
        }
        __builtin_amdgcn_sched_barrier(0);
        __builtin_amdgcn_s_setprio(1);
#pragma unroll
        for (int q = 0; q < MPP; ++q) {
          bf16x8 a0 = cur[q][0], a1 = cur[q][1];
#pragma unroll
          for (int ni = 0; ni < 4; ++ni) {
            acc[p * MPP + q][ni] = __builtin_amdgcn_mfma_f32_16x16x32_bf16(
                a0, bfrag[ni][0], acc[p * MPP + q][ni], 0, 0, 0);
            acc[p * MPP + q][ni] = __builtin_amdgcn_mfma_f32_16x16x32_bf16(
                a1, bfrag[ni][1], acc[p * MPP + q][ni], 0, 0, 0);
          }
        }
        __builtin_amdgcn_s_setprio(0);
      }
    } else {
      // -------- schedule B (MFMA-first, 2-deep; antiphase cover) --------
      // pre-fill A1 so the pipeline is 2 deep entering phase 0
#pragma unroll
      for (int q = 0; q < MPP; ++q) {
        const int ar = wm * (MB64 * 32) + (MPP + q) * 16 + lm;
        afB[q][0] = *(const bf16x8*)(la + ar * 128 + colb0);
        afB[q][1] = *(const bf16x8*)(la + ar * 128 + colb1);
      }
#pragma unroll
      for (int p = 0; p < 4; ++p) {
        auto& cur = (p & 1) ? afB : afA;
        // need A(p); only A(p+1)'s reads may be outstanding
        if (p < 3) {
          if constexpr (MPP == 2)
            asm volatile("s_waitcnt lgkmcnt(4)" ::: "memory");
          else
            asm volatile("s_waitcnt lgkmcnt(2)" ::: "memory");
        } else {
          asm volatile("s_waitcnt lgkmcnt(0)" ::: "memory");
        }
        __builtin_amdgcn_sched_barrier(0);
        __builtin_amdgcn_s_setprio(1);
#pragma unroll
        for (int q = 0; q < MPP; ++q) {
          bf16x8 a0 = cur[q][0], a1 = cur[q][1];
#pragma unroll
          for (int ni = 0; ni < 4; ++ni) {
            acc[p * MPP + q][ni] = __builtin_amdgcn_mfma_f32_16x16x32_bf16(
                a0, bfrag[ni][0], acc[p * MPP + q][ni], 0, 0, 0);
            acc[p * MPP + q][ni] = __builtin_amdgcn_mfma_f32_16x16x32_bf16(
                a1, bfrag[ni][1], acc[p * MPP + q][ni], 0, 0, 0);
          }
        }
        __builtin_amdgcn_s_setprio(0);
        if (p + 2 < 4) {
          // refill the buffer just consumed ((p+2)&1 == p&1)
#pragma unroll
          for (int q = 0; q < MPP; ++q) {
            const int ar = wm * (MB64 * 32) + ((p + 2) * MPP + q) * 16 + lm;
            cur[q][0] = *(const bf16x8*)(la + ar * 128 + colb0);
            cur[q][1] = *(const bf16x8*)(la + ar * 128 + colb1);
          }
        }
      }
    }
    __syncthreads();  // t+1 landed + slot-reuse WAR done (lgkm drained)
  }

#pragma unroll
  for (int ni = 0; ni < 4; ++ni) {
    const size_t col = bn + wn * 64 + ni * 16 + lm;
    const float bv = bias[col];
#pragma unroll
    for (int mi = 0; mi < MI; ++mi) {
#pragma unroll
      for (int r = 0; r < 4; ++r) {
        const size_t row = bm + wm * (MB64 * 32) + mi * 16 + lg * 4 + r;
        const float v = acc[mi][ni][r] + bv;
        if (OUT_BF16)
          ((bf16*)C)[row * N + col] = __float2bfloat16(v);
        else
          ((float*)C)[row * N + col] = v;
      }
    }
  }
}

// ---------------- RoPE on Q: [b][t][h*128+d] -> [b][h][t][d] ----------------
__global__ __launch_bounds__(256) void k_rope_q(
    const uint32_t* __restrict__ qin, const float* __restrict__ fc,
    const float* __restrict__ fs, uint32_t* __restrict__ qout) {
  const int tid = blockIdx.x * 256 + threadIdx.x;
  const int i = tid & 63;
  const int h = (tid >> 6) & 31;
  const int t = (tid >> 11) & 2047;
  const int b = tid >> 22;
  const uint32_t u = qin[tid];
  const float t0 = bf2f((uint16_t)(u & 0xffff));
  const float t1 = bf2f((uint16_t)(u >> 16));
  const float c = fc[t * 64 + i];
  const float s = fs[t * 64 + i];
  const float r0 = t0 * c - t1 * s;
  const float r1 = t0 * s + t1 * c;
  const uint32_t o = ((uint32_t)f2bf(r1) << 16) | f2bf(r0);
  qout[(((size_t)(b * 32 + h)) * 2048 + t) * 64 + i] = o;
}

// ---------------- RoPE on K part of KV ----------------
__global__ __launch_bounds__(256) void k_rope_k(
    const uint32_t* __restrict__ kvin, const float* __restrict__ fc,
    const float* __restrict__ fs, uint32_t* __restrict__ kout) {
  const int tid = blockIdx.x * 256 + threadIdx.x;
  const int i = tid & 63;
  const int kvh = (tid >> 6) & 7;
  const int t = (tid >> 9) & 2047;
  const int b = tid >> 20;
  const uint32_t u = kvin[((size_t)(b * 2048 + t)) * 1024 + kvh * 64 + i];
  const float t0 = bf2f((uint16_t)(u & 0xffff));
  const float t1 = bf2f((uint16_t)(u >> 16));
  const float c = fc[t * 64 + i];
  const float s = fs[t * 64 + i];
  const float r0 = t0 * c - t1 * s;
  const float r1 = t0 * s + t1 * c;
  const uint32_t o = ((uint32_t)f2bf(r1) << 16) | f2bf(r0);
  kout[(((size_t)(b * 8 + kvh)) * 2048 + t) * 64 + i] = o;
}

// ---------------- V transpose -> [b][kvh][d][t] ----------------
__global__ __launch_bounds__(256) void k_vt(const bf16* __restrict__ kv,
                                            bf16* __restrict__ vt) {
  __shared__ __align__(16) bf16 tile[64][130];
  const int bh = blockIdx.y;
  const int b = bh >> 3, kvh = bh & 7;
  const int t0 = blockIdx.x * 64;
  const int tid = threadIdx.x;
  const int d0 = (tid & 15) * 8;
  const int tr = tid >> 4;
#pragma unroll
  for (int j = 0; j < 4; ++j) {
    const int trow = tr + j * 16;
    const bf16* src =
        kv + ((size_t)(b * 2048) + t0 + trow) * 2048 + 1024 + kvh * 128 + d0;
    uint4 v = *(const uint4*)src;
    uint32_t* dst = (uint32_t*)&tile[trow][d0];
    dst[0] = v.x; dst[1] = v.y; dst[2] = v.z; dst[3] = v.w;
  }
  __syncthreads();
  const int d = tid >> 1;
  const int th = (tid & 1) * 32;
  uint4* out = (uint4*)(vt + (((size_t)bh) * 128 + d) * 2048 + t0 + th);
  union { bf16 h; uint16_t u; } cv;
#pragma unroll
  for (int j = 0; j < 4; ++j) {
    uint32_t wds[4];
#pragma unroll
    for (int p = 0; p < 4; ++p) {
      cv.h = tile[th + j * 8 + p * 2][d];
      uint32_t lo = cv.u;
      cv.h = tile[th + j * 8 + p * 2 + 1][d];
      wds[p] = lo | ((uint32_t)cv.u << 16);
    }
    uint4 val; val.x = wds[0]; val.y = wds[1]; val.z = wds[2]; val.w = wds[3];
    out[j] = val;
  }
}

// ---------------- causal GQA flash attention, 8-warp 32x32 swapped-QK^T ----
// SAFE-SYNC + T5 setprio + T13 defer-max + XCD-aware bh remap (r15 verified).
__global__ __launch_bounds__(512) void k_attn(
    const bf16* __restrict__ Q, const bf16* __restrict__ Kr,
    const bf16* __restrict__ Vt, bf16* __restrict__ Y) {
  constexpr int T = 2048;
  __shared__ __align__(16) char lds[65536];  // [2][K 16KB | V 16KB]
  const int tid = threadIdx.x;
  const int lane = tid & 63;
  const int w = tid >> 6;
  const int l31 = lane & 31;
  const int hi = lane >> 5;

  const int n = blockIdx.x;
  const int qc = 7 - (n >> 6);  // heavy-first
  const int g = n & 63;
  const int bh = ((g & 7) << 3) | (g >> 3);  // XCD x <- 2 full GQA quads
  const int b = bh >> 5, h = bh & 31, kvh = h >> 2;

  const int qrow = qc * 256 + w * 32 + l31;
  const int qmaxw = qc * 256 + w * 32 + 31;
  const int NT = qc * 4 + 4;

  const bf16* qptr = Q + (((size_t)(b * 32 + h)) * T + qrow) * 128 + hi * 8;
  bf16x8 qf[8];
#pragma unroll
  for (int kt = 0; kt < 8; ++kt) qf[kt] = *(const bf16x8*)(qptr + kt * 16);

  const char* kg = (const char*)(Kr + ((size_t)(b * 8 + kvh)) * T * 128);
  const char* vg = (const char*)(Vt + ((size_t)(b * 8 + kvh)) * 128 * T);
  const char* ksrc[2];
  const char* vsrc[2];
  int kdst[2], vdst[2];
#pragma unroll
  for (int j = 0; j < 2; ++j) {
    const int o = j * 8192 + tid * 16;
    const int krow = o >> 8, kin = o & 255;
    ksrc[j] = kg + (size_t)krow * 256 + (kin ^ ((krow & 15) << 4));
    kdst[j] = o;
    const int vrow = o >> 7, vin = o & 127;
    vsrc[j] = vg + (size_t)vrow * (T * 2) + (vin ^ ((vrow & 7) << 4));
    vdst[j] = 16384 + o;
  }

  f32x16 oacc[4];
#pragma unroll
  for (int d = 0; d < 4; ++d)
#pragma unroll
    for (int r = 0; r < 16; ++r) oacc[d][r] = 0.f;
  float m = -1e30f, l = 0.f;
  const float c1 = 0.08838834764831845f * 1.44269504089f;  // scale*log2e

  // prologue: stage tile 0 -> buf 0
#pragma unroll
  for (int j = 0; j < 2; ++j) {
    gld16(lds + kdst[j], ksrc[j]);
    gld16(lds + vdst[j], vsrc[j]);
  }

  for (int it = 0; it < NT; ++it) {
    const int buf = it & 1;
    __syncthreads();  // drains all vmcnt (tile-it staging) + block barrier

    if (it + 1 < NT) {  // stage next tile into the other buffer (overlaps)
      const int nb = buf ^ 1;
      const size_t ko = (size_t)(it + 1) * 16384;
      const size_t vo = (size_t)(it + 1) * 128;
#pragma unroll
      for (int j = 0; j < 2; ++j) {
        gld16(lds + nb * 32768 + kdst[j], ksrc[j] + ko);
        gld16(lds + nb * 32768 + vdst[j], vsrc[j] + vo);
      }
    }

    const int kt0 = it * 64;
    if (kt0 <= qmaxw) {  // warp-uniform: skip fully-masked tiles
      const char* kb = lds + buf * 32768;
      const char* vb = kb + 16384;

      // S^T = K Q^T  (two 32-key subtiles)
      f32x16 s0, s1;
#pragma unroll
      for (int r = 0; r < 16; ++r) { s0[r] = 0.f; s1[r] = 0.f; }
      const int kswz = (l31 & 15) << 4;
      __builtin_amdgcn_s_setprio(1);
#pragma unroll
      for (int kt = 0; kt < 8; ++kt) {
        const int cb = (kt * 32 + hi * 16) ^ kswz;
        bf16x8 kf0 = *(const bf16x8*)(kb + l31 * 256 + cb);
        bf16x8 kf1 = *(const bf16x8*)(kb + (32 + l31) * 256 + cb);
        s0 = __builtin_amdgcn_mfma_f32_32x32x16_bf16(kf0, qf[kt], s0, 0, 0, 0);
        s1 = __builtin_amdgcn_mfma_f32_32x32x16_bf16(kf1, qf[kt], s1, 0, 0, 0);
      }
      __builtin_amdgcn_s_setprio(0);

      // mask + scale (log2 units) + row max
      float tmax = -1e30f;
#pragma unroll
      for (int r = 0; r < 16; ++r) {
        const int key0 = kt0 + (r & 3) + 8 * (r >> 2) + 4 * hi;
        float v0 = s0[r] * c1;
        v0 = (key0 <= qrow) ? v0 : -1e30f;
        s0[r] = v0; tmax = fmaxf(tmax, v0);
        float v1 = s1[r] * c1;
        v1 = (key0 + 32 <= qrow) ? v1 : -1e30f;
        s1[r] = v1; tmax = fmaxf(tmax, v1);
      }
      tmax = fmaxf(tmax, __shfl_xor(tmax, 32));

      // online update with defer-max (THR ~ 8 nats = 11.5 log2-units)
      if (!__all(tmax <= m + 11.5f)) {
        const float mn = fmaxf(m, tmax);
        const float alpha = __builtin_amdgcn_exp2f(m - mn);
        m = mn;
        l *= alpha;
        float aw[16];
#pragma unroll
        for (int g2 = 0; g2 < 4; ++g2)
#pragma unroll
          for (int c = 0; c < 4; ++c)
            aw[g2 * 4 + c] = __shfl(alpha, g2 * 8 + hi * 4 + c, 64);
#pragma unroll
        for (int r = 0; r < 16; ++r) {
          const float a2 = aw[(r >> 2) * 4 + (r & 3)];
          oacc[0][r] *= a2; oacc[1][r] *= a2;
          oacc[2][r] *= a2; oacc[3][r] *= a2;
        }
      }

      // P = exp2(s - m), row sum
      float ls = 0.f;
#pragma unroll
      for (int r = 0; r < 16; ++r) {
        const float p0 = __builtin_amdgcn_exp2f(s0[r] - m); s0[r] = p0; ls += p0;
        const float p1 = __builtin_amdgcn_exp2f(s1[r] - m); s1[r] = p1; ls += p1;
      }
      l += ls + __shfl_xor(ls, 32);

      // PV: 4 k-steps of 16 keys; A-words via cvt_pk + lane^32 exchange
#pragma unroll
      for (int t = 0; t < 4; ++t) {
        uint32_t a0, a1, b0, b1;
        if (t == 0) {
          a0 = pk2(s0[0], s0[1]); a1 = pk2(s0[2], s0[3]);
          b0 = pk2(s0[4], s0[5]); b1 = pk2(s0[6], s0[7]);
        } else if (t == 1) {
          a0 = pk2(s0[8], s0[9]); a1 = pk2(s0[10], s0[11]);
          b0 = pk2(s0[12], s0[13]); b1 = pk2(s0[14], s0[15]);
        } else if (t == 2) {
          a0 = pk2(s1[0], s1[1]); a1 = pk2(s1[2], s1[3]);
          b0 = pk2(s1[4], s1[5]); b1 = pk2(s1[6], s1[7]);
        } else {
          a0 = pk2(s1[8], s1[9]); a1 = pk2(s1[10], s1[11]);
          b0 = pk2(s1[12], s1[13]); b1 = pk2(s1[14], s1[15]);
        }
        const uint32_t sa0 = __shfl_xor(a0, 32), sa1 = __shfl_xor(a1, 32);
        const uint32_t sb0 = __shfl_xor(b0, 32), sb1 = __shfl_xor(b1, 32);
        union { uint32_t u[4]; bf16x8 v; } A;
        A.u[0] = hi ? sb0 : a0;
        A.u[1] = hi ? sb1 : a1;
        A.u[2] = hi ? b0 : sa0;
        A.u[3] = hi ? b1 : sa1;
        __builtin_amdgcn_s_setprio(1);
#pragma unroll
        for (int d = 0; d < 4; ++d) {
          const int vrow = d * 32 + l31;
          const int vcb = (32 * t + 16 * hi) ^ ((vrow & 7) << 4);
          bf16x8 vf = *(const bf16x8*)(vb + vrow * 128 + vcb);
          oacc[d] = __builtin_amdgcn_mfma_f32_32x32x16_bf16(A.v, vf, oacc[d], 0, 0, 0);
        }
        __builtin_amdgcn_s_setprio(0);
      }
    }
    __syncthreads();  // all reads of buf done before it is overwritten
  }

  // epilogue: 1/l redistribution + store
  const float linv = 1.0f / l;
  float lw[16];
#pragma unroll
  for (int g2 = 0; g2 < 4; ++g2)
#pragma unroll
    for (int c = 0; c < 4; ++c)
      lw[g2 * 4 + c] = __shfl(linv, g2 * 8 + hi * 4 + c, 64);
  bf16* yb = Y + ((size_t)b * T) * 4096 + h * 128 + l31;
#pragma unroll
  for (int d = 0; d < 4; ++d)
#pragma unroll
    for (int r = 0; r < 16; ++r) {
      const int qp = (r & 3) + 8 * (r >> 2) + 4 * hi;
      const size_t trow = qc * 256 + w * 32 + qp;
      yb[trow * 4096 + d * 32] =
          __float2bfloat16(oacc[d][r] * lw[(r >> 2) * 4 + (r & 3)]);
    }
}

// ---------------- launch ----------------
extern "C" void kernel_launch(void* const* d_in, const int* in_sizes, int n_in,
                              void* d_out, int out_size, void* d_ws, size_t ws_size,
                              hipStream_t stream) {
  const float* x = (const float*)d_in[0];
  const float* fcos = (const float*)d_in[1];
  const float* fsin = (const float*)d_in[2];
  const float* wq = (const float*)d_in[3];
  const float* bq = (const float*)d_in[4];
  const float* wkv = (const float*)d_in[5];
  const float* bkv = (const float*)d_in[6];
  const float* wp = (const float*)d_in[7];
  const float* bp = (const float*)d_in[8];

  char* ws = (char*)d_ws;
  size_t off = 0;
  auto alloc = [&](size_t bytes) {
    char* p = ws + off;
    off += (bytes + 255) & ~(size_t)255;
    return p;
  };
  bf16* xb = (bf16*)alloc(16777216ull * 2);    // x bf16 [b][t][4096]
  bf16* wqb = (bf16*)alloc(16777216ull * 2);   // [4096][4096]
  bf16* wkvb = (bf16*)alloc(8388608ull * 2);   // [2048][4096]
  bf16* wpb = (bf16*)alloc(16777216ull * 2);
  bf16* qb = (bf16*)alloc(16777216ull * 2);    // q pre-rope; reused as Y
  bf16* kvb = (bf16*)alloc(8388608ull * 2);    // kv pre-rope [b][t][2048]
  bf16* qr = (bf16*)alloc(16777216ull * 2);    // roped Q [b][h][t][128]
  bf16* kr = (bf16*)alloc(4194304ull * 2);     // roped K [b][kvh][t][128]
  bf16* vt = (bf16*)alloc(4194304ull * 2);     // V^T [b][kvh][128][t]
  bf16* yb = qb;                               // attn out aliases qb

  k_cast4<<<57344, 256, 0, stream>>>((const float4*)x, (const float4*)wq,
                                     (const float4*)wkv, (const float4*)wp,
                                     (uint2*)xb, (uint2*)wqb, (uint2*)wkvb,
                                     (uint2*)wpb);

  // Q: 256x256 tile, grid 256 (1/CU exact). KV: 128x256 tile, grid 32x8=256.
  k_gemm256<1, 4><<<256, 512, 0, stream>>>(xb, wqb, bq, qb, 4096, 4096, 4096, 16);
  k_gemm256<1, 2><<<256, 512, 0, stream>>>(xb, wkvb, bkv, kvb, 4096, 2048, 4096, 8);

  k_rope_q<<<32768, 256, 0, stream>>>((const uint32_t*)qb, fcos, fsin, (uint32_t*)qr);
  k_rope_k<<<8192, 256, 0, stream>>>((const uint32_t*)kvb, fcos, fsin, (uint32_t*)kr);
  k_vt<<<dim3(32, 16), 256, 0, stream>>>(kvb, vt);

  k_attn<<<512, 512, 0, stream>>>(qr, kr, vt, yb);

  k_gemm256<0, 4><<<256, 512, 0, stream>>>(yb, wpb, bp, d_out, 4096, 4096, 4096, 16);
}

// Round 17
// 476.374 us; speedup vs baseline: 1.0132x; 1.0132x over previous
//
#include <hip/hip_runtime.h>
#include <hip/hip_bf16.h>
#include <stdint.h>

typedef __hip_bfloat16 bf16;
typedef __attribute__((ext_vector_type(8))) __bf16 bf16x8;
typedef __attribute__((ext_vector_type(4))) float f32x4;
typedef __attribute__((ext_vector_type(16))) float f32x16;

__device__ __forceinline__ void gld16(void* lds, const void* g) {
  __builtin_amdgcn_global_load_lds(
      (const __attribute__((address_space(1))) void*)(uintptr_t)(g),
      (__attribute__((address_space(3))) void*)(uint32_t)(uintptr_t)(lds),
      16, 0, 0);
}

__device__ __forceinline__ uint16_t f2bf(float f) {
  union { bf16 h; uint16_t u; } x; x.h = __float2bfloat16(f); return x.u;
}
__device__ __forceinline__ float bf2f(uint16_t v) {
  union { uint32_t u; float f; } x; x.u = ((uint32_t)v) << 16; return x.f;
}
__device__ __forceinline__ uint32_t pk2(float lo, float hi) {
  uint32_t r;
  asm("v_cvt_pk_bf16_f32 %0, %1, %2" : "=v"(r) : "v"(lo), "v"(hi));
  return r;
}

// ------- fused f32 -> bf16 cast of x, wq, wkv, wp (one launch) -------
__global__ __launch_bounds__(256) void k_cast4(
    const float4* __restrict__ x, const float4* __restrict__ wq,
    const float4* __restrict__ wkv, const float4* __restrict__ wp,
    uint2* __restrict__ xb, uint2* __restrict__ wqb,
    uint2* __restrict__ wkvb, uint2* __restrict__ wpb) {
  int i = blockIdx.x * 256 + threadIdx.x;  // 0 .. 14680064
  const float4* src;
  uint2* dst;
  int o;
  if (i < 4194304) { src = x; dst = xb; o = i; }
  else if (i < 8388608) { src = wq; dst = wqb; o = i - 4194304; }
  else if (i < 10485760) { src = wkv; dst = wkvb; o = i - 8388608; }
  else { src = wp; dst = wpb; o = i - 10485760; }
  float4 v = src[o];
  uint32_t a = ((uint32_t)f2bf(v.y) << 16) | f2bf(v.x);
  uint32_t b = ((uint32_t)f2bf(v.w) << 16) | f2bf(v.z);
  dst[o] = make_uint2(a, b);
}

// ---------------- (MB64*64)x256 NT GEMM, counted-lgm pipelined K-loop -----
// ROUND-13 VERIFIED FORM (best of 6 structural variants: 45% MfmaUtil).
// One __syncthreads per K-tile; reads-first, stage-behind; ping-pong A-frag
// reads with counted lgkmcnt so read latency hides under the MFMA burst.
template <int OUT_BF16, int MB64>
__global__ __launch_bounds__(512, 2) void k_gemm256(
    const bf16* __restrict__ A, const bf16* __restrict__ B,
    const float* __restrict__ bias, void* __restrict__ C,
    int M, int N, int K, int gx) {
  constexpr int MPP = MB64 / 2;
  constexpr int MI = MB64 * 2;
  constexpr int ABYTES = MB64 * 8192;
  constexpr int SLOT = ABYTES + 32768;
  __shared__ __align__(16) char lds[2 * SLOT];
  const int tid = threadIdx.x;
  const int lane = tid & 63;
  const int w = tid >> 6;
  const int wm = w >> 2;
  const int wn = w & 3;
  const int lm = lane & 15;
  const int lg = lane >> 4;

  const int nwg = gridDim.x;
  const int cpx = nwg >> 3;
  const int bid0 = blockIdx.x;
  const int bid = (bid0 & 7) * cpx + (bid0 >> 3);
  const int bx = bid % gx;
  const int by = bid / gx;
  const size_t bm = (size_t)by * (MB64 * 64);
  const size_t bn = (size_t)bx * 256;

  const int srow = tid >> 3;
  const int scb = ((tid & 7) * 16) ^ ((srow & 7) << 4);
  const char* asrc[MB64];
  const char* bsrc[4];
#pragma unroll
  for (int j = 0; j < MB64; ++j)
    asrc[j] = (const char*)(A + (bm + j * 64 + srow) * K) + scb;
#pragma unroll
  for (int j = 0; j < 4; ++j)
    bsrc[j] = (const char*)(B + (bn + j * 64 + srow) * K) + scb;
  const int ldst = tid * 16;

  const int colb0 = (lg * 16) ^ ((lm & 7) << 4);
  const int colb1 = colb0 ^ 64;

  f32x4 acc[MI][4];
#pragma unroll
  for (int i = 0; i < MI; ++i)
#pragma unroll
    for (int j = 0; j < 4; ++j) acc[i][j] = (f32x4){0.f, 0.f, 0.f, 0.f};

  const int NT = K >> 6;

  {
    char* la = lds;
    char* lb = lds + ABYTES;
#pragma unroll
    for (int j = 0; j < MB64; ++j) gld16(la + j * 8192 + ldst, asrc[j]);
#pragma unroll
    for (int j = 0; j < 4; ++j) gld16(lb + j * 8192 + ldst, bsrc[j]);
  }
  __syncthreads();  // tile 0 landed

  for (int t = 0; t < NT; ++t) {
    const int slot = t & 1;
    const char* la = lds + slot * SLOT;
    const char* lb = la + ABYTES;

    bf16x8 bfrag[4][2];
#pragma unroll
    for (int ni = 0; ni < 4; ++ni) {
      const int br = wn * 64 + ni * 16 + lm;
      bfrag[ni][0] = *(const bf16x8*)(lb + br * 128 + colb0);
      bfrag[ni][1] = *(const bf16x8*)(lb + br * 128 + colb1);
    }
    bf16x8 afA[MPP][2], afB[MPP][2];
#pragma unroll
    for (int q = 0; q < MPP; ++q) {
      const int ar = wm * (MB64 * 32) + q * 16 + lm;
      afA[q][0] = *(const bf16x8*)(la + ar * 128 + colb0);
      afA[q][1] = *(const bf16x8*)(la + ar * 128 + colb1);
    }

    if (t + 1 < NT) {
      char* na = lds + (slot ^ 1) * SLOT;
      char* nb = na + ABYTES;
      const size_t ko = (size_t)(t + 1) * 128;
#pragma unroll
      for (int j = 0; j < MB64; ++j) gld16(na + j * 8192 + ldst, asrc[j] + ko);
#pragma unroll
      for (int j = 0; j < 4; ++j) gld16(nb + j * 8192 + ldst, bsrc[j] + ko);
    }

#pragma unroll
    for (int p = 0; p < 4; ++p) {
      auto& cur = (p & 1) ? afB : afA;
      auto& nxt = (p & 1) ? afA : afB;
      if (p < 3) {
#pragma unroll
        for (int q = 0; q < MPP; ++q) {
          const int ar = wm * (MB64 * 32) + ((p + 1) * MPP + q) * 16 + lm;
          nxt[q][0] = *(const bf16x8*)(la + ar * 128 + colb0);
          nxt[q][1] = *(const bf16x8*)(la + ar * 128 + colb1);
        }
        if constexpr (MPP == 2)
          asm volatile("s_waitcnt lgkmcnt(4)" ::: "memory");
        else
          asm volatile("s_waitcnt lgkmcnt(2)" ::: "memory");
      } else {
        asm volatile("s_waitcnt lgkmcnt(0)" ::: "memory");
      }
      __builtin_amdgcn_sched_barrier(0);
      __builtin_amdgcn_s_setprio(1);
#pragma unroll
      for (int q = 0; q < MPP; ++q) {
        bf16x8 a0 = cur[q][0], a1 = cur[q][1];
#pragma unroll
        for (int ni = 0; ni < 4; ++ni) {
          acc[p * MPP + q][ni] = __builtin_amdgcn_mfma_f32_16x16x32_bf16(
              a0, bfrag[ni][0], acc[p * MPP + q][ni], 0, 0, 0);
          acc[p * MPP + q][ni] = __builtin_amdgcn_mfma_f32_16x16x32_bf16(
              a1, bfrag[ni][1], acc[p * MPP + q][ni], 0, 0, 0);
        }
      }
      __builtin_amdgcn_s_setprio(0);
    }
    __syncthreads();  // t+1 landed + slot-reuse WAR done
  }

#pragma unroll
  for (int ni = 0; ni < 4; ++ni) {
    const size_t col = bn + wn * 64 + ni * 16 + lm;
    const float bv = bias[col];
#pragma unroll
    for (int mi = 0; mi < MI; ++mi) {
#pragma unroll
      for (int r = 0; r < 4; ++r) {
        const size_t row = bm + wm * (MB64 * 32) + mi * 16 + lg * 4 + r;
        const float v = acc[mi][ni][r] + bv;
        if (OUT_BF16)
          ((bf16*)C)[row * N + col] = __float2bfloat16(v);
        else
          ((float*)C)[row * N + col] = v;
      }
    }
  }
}

// ---------------- RoPE on Q: [b][t][h*128+d] -> [b][h][t][d] ----------------
__global__ __launch_bounds__(256) void k_rope_q(
    const uint32_t* __restrict__ qin, const float* __restrict__ fc,
    const float* __restrict__ fs, uint32_t* __restrict__ qout) {
  const int tid = blockIdx.x * 256 + threadIdx.x;
  const int i = tid & 63;
  const int h = (tid >> 6) & 31;
  const int t = (tid >> 11) & 2047;
  const int b = tid >> 22;
  const uint32_t u = qin[tid];
  const float t0 = bf2f((uint16_t)(u & 0xffff));
  const float t1 = bf2f((uint16_t)(u >> 16));
  const float c = fc[t * 64 + i];
  const float s = fs[t * 64 + i];
  const float r0 = t0 * c - t1 * s;
  const float r1 = t0 * s + t1 * c;
  const uint32_t o = ((uint32_t)f2bf(r1) << 16) | f2bf(r0);
  qout[(((size_t)(b * 32 + h)) * 2048 + t) * 64 + i] = o;
}

// ---------------- RoPE on K part of KV ----------------
__global__ __launch_bounds__(256) void k_rope_k(
    const uint32_t* __restrict__ kvin, const float* __restrict__ fc,
    const float* __restrict__ fs, uint32_t* __restrict__ kout) {
  const int tid = blockIdx.x * 256 + threadIdx.x;
  const int i = tid & 63;
  const int kvh = (tid >> 6) & 7;
  const int t = (tid >> 9) & 2047;
  const int b = tid >> 20;
  const uint32_t u = kvin[((size_t)(b * 2048 + t)) * 1024 + kvh * 64 + i];
  const float t0 = bf2f((uint16_t)(u & 0xffff));
  const float t1 = bf2f((uint16_t)(u >> 16));
  const float c = fc[t * 64 + i];
  const float s = fs[t * 64 + i];
  const float r0 = t0 * c - t1 * s;
  const float r1 = t0 * s + t1 * c;
  const uint32_t o = ((uint32_t)f2bf(r1) << 16) | f2bf(r0);
  kout[(((size_t)(b * 8 + kvh)) * 2048 + t) * 64 + i] = o;
}

// ---------------- V transpose -> [b][kvh][d][t] ----------------
__global__ __launch_bounds__(256) void k_vt(const bf16* __restrict__ kv,
                                            bf16* __restrict__ vt) {
  __shared__ __align__(16) bf16 tile[64][130];
  const int bh = blockIdx.y;
  const int b = bh >> 3, kvh = bh & 7;
  const int t0 = blockIdx.x * 64;
  const int tid = threadIdx.x;
  const int d0 = (tid & 15) * 8;
  const int tr = tid >> 4;
#pragma unroll
  for (int j = 0; j < 4; ++j) {
    const int trow = tr + j * 16;
    const bf16* src =
        kv + ((size_t)(b * 2048) + t0 + trow) * 2048 + 1024 + kvh * 128 + d0;
    uint4 v = *(const uint4*)src;
    uint32_t* dst = (uint32_t*)&tile[trow][d0];
    dst[0] = v.x; dst[1] = v.y; dst[2] = v.z; dst[3] = v.w;
  }
  __syncthreads();
  const int d = tid >> 1;
  const int th = (tid & 1) * 32;
  uint4* out = (uint4*)(vt + (((size_t)bh) * 128 + d) * 2048 + t0 + th);
  union { bf16 h; uint16_t u; } cv;
#pragma unroll
  for (int j = 0; j < 4; ++j) {
    uint32_t wds[4];
#pragma unroll
    for (int p = 0; p < 4; ++p) {
      cv.h = tile[th + j * 8 + p * 2][d];
      uint32_t lo = cv.u;
      cv.h = tile[th + j * 8 + p * 2 + 1][d];
      wds[p] = lo | ((uint32_t)cv.u << 16);
    }
    uint4 val; val.x = wds[0]; val.y = wds[1]; val.z = wds[2]; val.w = wds[3];
    out[j] = val;
  }
}

// ---------------- causal GQA flash attention, 8-warp 32x32 swapped-QK^T ----
// SAFE-SYNC + T5 setprio + T13 defer-max + XCD-aware bh remap (r15 verified).
__global__ __launch_bounds__(512) void k_attn(
    const bf16* __restrict__ Q, const bf16* __restrict__ Kr,
    const bf16* __restrict__ Vt, bf16* __restrict__ Y) {
  constexpr int T = 2048;
  __shared__ __align__(16) char lds[65536];  // [2][K 16KB | V 16KB]
  const int tid = threadIdx.x;
  const int lane = tid & 63;
  const int w = tid >> 6;
  const int l31 = lane & 31;
  const int hi = lane >> 5;

  const int n = blockIdx.x;
  const int qc = 7 - (n >> 6);  // heavy-first
  const int g = n & 63;
  const int bh = ((g & 7) << 3) | (g >> 3);  // XCD x <- 2 full GQA quads
  const int b = bh >> 5, h = bh & 31, kvh = h >> 2;

  const int qrow = qc * 256 + w * 32 + l31;
  const int qmaxw = qc * 256 + w * 32 + 31;
  const int NT = qc * 4 + 4;

  const bf16* qptr = Q + (((size_t)(b * 32 + h)) * T + qrow) * 128 + hi * 8;
  bf16x8 qf[8];
#pragma unroll
  for (int kt = 0; kt < 8; ++kt) qf[kt] = *(const bf16x8*)(qptr + kt * 16);

  const char* kg = (const char*)(Kr + ((size_t)(b * 8 + kvh)) * T * 128);
  const char* vg = (const char*)(Vt + ((size_t)(b * 8 + kvh)) * 128 * T);
  const char* ksrc[2];
  const char* vsrc[2];
  int kdst[2], vdst[2];
#pragma unroll
  for (int j = 0; j < 2; ++j) {
    const int o = j * 8192 + tid * 16;
    const int krow = o >> 8, kin = o & 255;
    ksrc[j] = kg + (size_t)krow * 256 + (kin ^ ((krow & 15) << 4));
    kdst[j] = o;
    const int vrow = o >> 7, vin = o & 127;
    vsrc[j] = vg + (size_t)vrow * (T * 2) + (vin ^ ((vrow & 7) << 4));
    vdst[j] = 16384 + o;
  }

  f32x16 oacc[4];
#pragma unroll
  for (int d = 0; d < 4; ++d)
#pragma unroll
    for (int r = 0; r < 16; ++r) oacc[d][r] = 0.f;
  float m = -1e30f, l = 0.f;
  const float c1 = 0.08838834764831845f * 1.44269504089f;  // scale*log2e

  // prologue: stage tile 0 -> buf 0
#pragma unroll
  for (int j = 0; j < 2; ++j) {
    gld16(lds + kdst[j], ksrc[j]);
    gld16(lds + vdst[j], vsrc[j]);
  }

  for (int it = 0; it < NT; ++it) {
    const int buf = it & 1;
    __syncthreads();  // drains all vmcnt (tile-it staging) + block barrier

    if (it + 1 < NT) {  // stage next tile into the other buffer (overlaps)
      const int nb = buf ^ 1;
      const size_t ko = (size_t)(it + 1) * 16384;
      const size_t vo = (size_t)(it + 1) * 128;
#pragma unroll
      for (int j = 0; j < 2; ++j) {
        gld16(lds + nb * 32768 + kdst[j], ksrc[j] + ko);
        gld16(lds + nb * 32768 + vdst[j], vsrc[j] + vo);
      }
    }

    const int kt0 = it * 64;
    if (kt0 <= qmaxw) {  // warp-uniform: skip fully-masked tiles
      const char* kb = lds + buf * 32768;
      const char* vb = kb + 16384;

      // S^T = K Q^T  (two 32-key subtiles)
      f32x16 s0, s1;
#pragma unroll
      for (int r = 0; r < 16; ++r) { s0[r] = 0.f; s1[r] = 0.f; }
      const int kswz = (l31 & 15) << 4;
      __builtin_amdgcn_s_setprio(1);
#pragma unroll
      for (int kt = 0; kt < 8; ++kt) {
        const int cb = (kt * 32 + hi * 16) ^ kswz;
        bf16x8 kf0 = *(const bf16x8*)(kb + l31 * 256 + cb);
        bf16x8 kf1 = *(const bf16x8*)(kb + (32 + l31) * 256 + cb);
        s0 = __builtin_amdgcn_mfma_f32_32x32x16_bf16(kf0, qf[kt], s0, 0, 0, 0);
        s1 = __builtin_amdgcn_mfma_f32_32x32x16_bf16(kf1, qf[kt], s1, 0, 0, 0);
      }
      __builtin_amdgcn_s_setprio(0);

      // mask + scale (log2 units) + row max
      float tmax = -1e30f;
#pragma unroll
      for (int r = 0; r < 16; ++r) {
        const int key0 = kt0 + (r & 3) + 8 * (r >> 2) + 4 * hi;
        float v0 = s0[r] * c1;
        v0 = (key0 <= qrow) ? v0 : -1e30f;
        s0[r] = v0; tmax = fmaxf(tmax, v0);
        float v1 = s1[r] * c1;
        v1 = (key0 + 32 <= qrow) ? v1 : -1e30f;
        s1[r] = v1; tmax = fmaxf(tmax, v1);
      }
      tmax = fmaxf(tmax, __shfl_xor(tmax, 32));

      // online update with defer-max (THR ~ 8 nats = 11.5 log2-units)
      if (!__all(tmax <= m + 11.5f)) {
        const float mn = fmaxf(m, tmax);
        const float alpha = __builtin_amdgcn_exp2f(m - mn);
        m = mn;
        l *= alpha;
        float aw[16];
#pragma unroll
        for (int g2 = 0; g2 < 4; ++g2)
#pragma unroll
          for (int c = 0; c < 4; ++c)
            aw[g2 * 4 + c] = __shfl(alpha, g2 * 8 + hi * 4 + c, 64);
#pragma unroll
        for (int r = 0; r < 16; ++r) {
          const float a2 = aw[(r >> 2) * 4 + (r & 3)];
          oacc[0][r] *= a2; oacc[1][r] *= a2;
          oacc[2][r] *= a2; oacc[3][r] *= a2;
        }
      }

      // P = exp2(s - m), row sum
      float ls = 0.f;
#pragma unroll
      for (int r = 0; r < 16; ++r) {
        const float p0 = __builtin_amdgcn_exp2f(s0[r] - m); s0[r] = p0; ls += p0;
        const float p1 = __builtin_amdgcn_exp2f(s1[r] - m); s1[r] = p1; ls += p1;
      }
      l += ls + __shfl_xor(ls, 32);

      // PV: 4 k-steps of 16 keys; A-words via cvt_pk + lane^32 exchange
#pragma unroll
      for (int t = 0; t < 4; ++t) {
        uint32_t a0, a1, b0, b1;
        if (t == 0) {
          a0 = pk2(s0[0], s0[1]); a1 = pk2(s0[2], s0[3]);
          b0 = pk2(s0[4], s0[5]); b1 = pk2(s0[6], s0[7]);
        } else if (t == 1) {
          a0 = pk2(s0[8], s0[9]); a1 = pk2(s0[10], s0[11]);
          b0 = pk2(s0[12], s0[13]); b1 = pk2(s0[14], s0[15]);
        } else if (t == 2) {
          a0 = pk2(s1[0], s1[1]); a1 = pk2(s1[2], s1[3]);
          b0 = pk2(s1[4], s1[5]); b1 = pk2(s1[6], s1[7]);
        } else {
          a0 = pk2(s1[8], s1[9]); a1 = pk2(s1[10], s1[11]);
          b0 = pk2(s1[12], s1[13]); b1 = pk2(s1[14], s1[15]);
        }
        const uint32_t sa0 = __shfl_xor(a0, 32), sa1 = __shfl_xor(a1, 32);
        const uint32_t sb0 = __shfl_xor(b0, 32), sb1 = __shfl_xor(b1, 32);
        union { uint32_t u[4]; bf16x8 v; } A;
        A.u[0] = hi ? sb0 : a0;
        A.u[1] = hi ? sb1 : a1;
        A.u[2] = hi ? b0 : sa0;
        A.u[3] = hi ? b1 : sa1;
        __builtin_amdgcn_s_setprio(1);
#pragma unroll
        for (int d = 0; d < 4; ++d) {
          const int vrow = d * 32 + l31;
          const int vcb = (32 * t + 16 * hi) ^ ((vrow & 7) << 4);
          bf16x8 vf = *(const bf16x8*)(vb + vrow * 128 + vcb);
          oacc[d] = __builtin_amdgcn_mfma_f32_32x32x16_bf16(A.v, vf, oacc[d], 0, 0, 0);
        }
        __builtin_amdgcn_s_setprio(0);
      }
    }
    __syncthreads();  // all reads of buf done before it is overwritten
  }

  // epilogue: 1/l redistribution + store
  const float linv = 1.0f / l;
  float lw[16];
#pragma unroll
  for (int g2 = 0; g2 < 4; ++g2)
#pragma unroll
    for (int c = 0; c < 4; ++c)
      lw[g2 * 4 + c] = __shfl(linv, g2 * 8 + hi * 4 + c, 64);
  bf16* yb = Y + ((size_t)b * T) * 4096 + h * 128 + l31;
#pragma unroll
  for (int d = 0; d < 4; ++d)
#pragma unroll
    for (int r = 0; r < 16; ++r) {
      const int qp = (r & 3) + 8 * (r >> 2) + 4 * hi;
      const size_t trow = qc * 256 + w * 32 + qp;
      yb[trow * 4096 + d * 32] =
          __float2bfloat16(oacc[d][r] * lw[(r >> 2) * 4 + (r & 3)]);
    }
}

// ---------------- launch ----------------
extern "C" void kernel_launch(void* const* d_in, const int* in_sizes, int n_in,
                              void* d_out, int out_size, void* d_ws, size_t ws_size,
                              hipStream_t stream) {
  const float* x = (const float*)d_in[0];
  const float* fcos = (const float*)d_in[1];
  const float* fsin = (const float*)d_in[2];
  const float* wq = (const float*)d_in[3];
  const float* bq = (const float*)d_in[4];
  const float* wkv = (const float*)d_in[5];
  const float* bkv = (const float*)d_in[6];
  const float* wp = (const float*)d_in[7];
  const float* bp = (const float*)d_in[8];

  char* ws = (char*)d_ws;
  size_t off = 0;
  auto alloc = [&](size_t bytes) {
    char* p = ws + off;
    off += (bytes + 255) & ~(size_t)255;
    return p;
  };
  bf16* xb = (bf16*)alloc(16777216ull * 2);    // x bf16 [b][t][4096]
  bf16* wqb = (bf16*)alloc(16777216ull * 2);   // [4096][4096]
  bf16* wkvb = (bf16*)alloc(8388608ull * 2);   // [2048][4096]
  bf16* wpb = (bf16*)alloc(16777216ull * 2);
  bf16* qb = (bf16*)alloc(16777216ull * 2);    // q pre-rope; reused as Y
  bf16* kvb = (bf16*)alloc(8388608ull * 2);    // kv pre-rope [b][t][2048]
  bf16* qr = (bf16*)alloc(16777216ull * 2);    // roped Q [b][h][t][128]
  bf16* kr = (bf16*)alloc(4194304ull * 2);     // roped K [b][kvh][t][128]
  bf16* vt = (bf16*)alloc(4194304ull * 2);     // V^T [b][kvh][128][t]
  bf16* yb = qb;                               // attn out aliases qb

  k_cast4<<<57344, 256, 0, stream>>>((const float4*)x, (const float4*)wq,
                                     (const float4*)wkv, (const float4*)wp,
                                     (uint2*)xb, (uint2*)wqb, (uint2*)wkvb,
                                     (uint2*)wpb);

  // Q: 256x256 tile, grid 256 (1/CU exact). KV: 128x256 tile, grid 32x8=256.
  k_gemm256<1, 4><<<256, 512, 0, stream>>>(xb, wqb, bq, qb, 4096, 4096, 4096, 16);
  k_gemm256<1, 2><<<256, 512, 0, stream>>>(xb, wkvb, bkv, kvb, 4096, 2048, 4096, 8);

  k_rope_q<<<32768, 256, 0, stream>>>((const uint32_t*)qb, fcos, fsin, (uint32_t*)qr);
  k_rope_k<<<8192, 256, 0, stream>>>((const uint32_t*)kvb, fcos, fsin, (uint32_t*)kr);
  k_vt<<<dim3(32, 16), 256, 0, stream>>>(kvb, vt);

  k_attn<<<512, 512, 0, stream>>>(qr, kr, vt, yb);

  k_gemm256<0, 4><<<256, 512, 0, stream>>>(yb, wpb, bp, d_out, 4096, 4096, 4096, 16);
}